// Round 1
// 1138.000 us; speedup vs baseline: 1.0439x; 1.0439x over previous
//
#include <hip/hip_runtime.h>
#include <hip/hip_bf16.h>

typedef __bf16 bf16_t;
typedef __bf16 bf16x8 __attribute__((ext_vector_type(8)));
typedef float  f32x4  __attribute__((ext_vector_type(4)));
typedef unsigned int u32x4 __attribute__((ext_vector_type(4)));

#define NB 2
#define NS 2048
#define ND 1024
#define NH 16
#define NDH 64
#define NP 1024
#define NM (NB*NS)   // 4096 rows total

__device__ __forceinline__ bf16x8 load8(const bf16_t* p) {
  u32x4 u = *(const u32x4*)p;
  return __builtin_bit_cast(bf16x8, u);
}
__device__ __forceinline__ unsigned short bfb(float f) {
  return __builtin_bit_cast(unsigned short, (bf16_t)f);
}

// ---------------------------------------------------------------------------
// Cast x -> bf16 (coalesced float4 -> ushort4)
// ---------------------------------------------------------------------------
__global__ __launch_bounds__(256) void k_cast(
    const float* __restrict__ x, bf16_t* __restrict__ x_bf)
{
  const long NX4 = (long)NM * ND / 4;   // 1M float4 items
  long i0 = (long)blockIdx.x * blockDim.x + threadIdx.x;
  long stride = (long)gridDim.x * blockDim.x;
  for (long i = i0; i < NX4; i += stride) {
    float4 v = ((const float4*)x)[i];
    ushort4 pk;
    pk.x = bfb(v.x); pk.y = bfb(v.y); pk.z = bfb(v.z); pk.w = bfb(v.w);
    ((ushort4*)x_bf)[i] = pk;
  }
}

// ---------------------------------------------------------------------------
// Weight transpose via LDS tile: fp32 [K][N] -> bf16 [N][K], coalesced both ways
// (replaces the old scattered 2B-store transpose: 1 store = 1 64B sector)
// ---------------------------------------------------------------------------
__global__ __launch_bounds__(256) void k_wt(
    const float* __restrict__ Wq, const float* __restrict__ Wk,
    const float* __restrict__ Wv, const float* __restrict__ Wo,
    bf16_t* __restrict__ wtq, bf16_t* __restrict__ wtk,
    bf16_t* __restrict__ wtv, bf16_t* __restrict__ wto)
{
  __shared__ __align__(16) bf16_t tileT[64][72];  // [n][k], stride 144B (16B-aligned rows)
  const int w = blockIdx.z;
  const float* src = (w == 0) ? Wq : (w == 1) ? Wk : (w == 2) ? Wv : Wo;
  bf16_t*      dst = (w == 0) ? wtq : (w == 1) ? wtk : (w == 2) ? wtv : wto;
  const int k0 = blockIdx.x * 64, n0 = blockIdx.y * 64;
  const int tid = threadIdx.x;
  const int r = tid >> 4, c4 = (tid & 15) * 4;
#pragma unroll
  for (int rr = 0; rr < 4; ++rr) {
    const int row = rr * 16 + r;                  // k index within tile
    const float4 v = *(const float4*)&src[(long)(k0 + row) * NP + n0 + c4];
    tileT[c4 + 0][row] = (bf16_t)v.x;
    tileT[c4 + 1][row] = (bf16_t)v.y;
    tileT[c4 + 2][row] = (bf16_t)v.z;
    tileT[c4 + 3][row] = (bf16_t)v.w;
  }
  __syncthreads();
  const int nr = tid >> 2, kc = (tid & 3) * 16;
  const bf16x8 p0 = *(const bf16x8*)&tileT[nr][kc];
  const bf16x8 p1 = *(const bf16x8*)&tileT[nr][kc + 8];
  bf16_t* dp = dst + (long)(n0 + nr) * ND + k0 + kc;
  *(bf16x8*)dp = p0;
  *(bf16x8*)(dp + 8) = p1;
}

// ---------------------------------------------------------------------------
// QKV projection: C[4096 x 1024] = x_bf @ W, per z in {q,k,v}
// q (pre-scaled by 1/8, exact pow2), k stored [b][h][s][dh]; v transposed
// ---------------------------------------------------------------------------
__global__ __launch_bounds__(256) void k_gemm_proj(
    const bf16_t* __restrict__ Abf,
    const bf16_t* __restrict__ wtq, const bf16_t* __restrict__ wtk,
    const bf16_t* __restrict__ wtv,
    bf16_t* __restrict__ q_ws, bf16_t* __restrict__ k_ws, bf16_t* __restrict__ v_ws)
{
  const int z = blockIdx.z;
  const bf16_t* Wt = (z == 0) ? wtq : (z == 1) ? wtk : wtv;
  const int tm = blockIdx.x * 64;
  const int tn = blockIdx.y * 64;
  const int wave = threadIdx.x >> 6;
  const int lane = threadIdx.x & 63;
  const int l16 = lane & 15, quad = lane >> 4;

  const bf16_t* arow = Abf + (long)(tm + wave * 16 + l16) * ND;
  const bf16_t* brow[4];
#pragma unroll
  for (int nt = 0; nt < 4; ++nt)
    brow[nt] = Wt + (long)(tn + nt * 16 + l16) * ND;

  f32x4 acc[4] = {{0,0,0,0},{0,0,0,0},{0,0,0,0},{0,0,0,0}};
  for (int k0 = 0; k0 < ND; k0 += 32) {
    bf16x8 a = load8(arow + k0 + quad * 8);
#pragma unroll
    for (int nt = 0; nt < 4; ++nt) {
      bf16x8 bfrag = load8(brow[nt] + k0 + quad * 8);
      acc[nt] = __builtin_amdgcn_mfma_f32_16x16x32_bf16(a, bfrag, acc[nt], 0, 0, 0);
    }
  }

  const float qscale = (z == 0) ? 0.125f : 1.0f;  // fold 1/sqrt(DH) into Q (exact)
  const int m0 = tm + wave * 16 + quad * 4;
#pragma unroll
  for (int nt = 0; nt < 4; ++nt) {
    const int n = tn + nt * 16 + l16;
    const int h = n >> 6, dh = n & 63;
    if (z == 2) {
      // v transposed: [b][h][dh][s]; rows m0..m0+3 are consecutive s
      const int b = m0 >> 11, s0 = m0 & 2047;
      ushort4 pk;
      pk.x = bfb(acc[nt][0]); pk.y = bfb(acc[nt][1]);
      pk.z = bfb(acc[nt][2]); pk.w = bfb(acc[nt][3]);
      *(ushort4*)(v_ws + ((long)(b * NH + h) * NDH + dh) * NS + s0) = pk;
    } else {
      bf16_t* dst = (z == 0) ? q_ws : k_ws;
#pragma unroll
      for (int r = 0; r < 4; ++r) {
        const int m = m0 + r;
        const int b = m >> 11, s = m & 2047;
        dst[((long)(b * NH + h) * NS + s) * NDH + dh] = (bf16_t)(acc[nt][r] * qscale);
      }
    }
  }
}

// ---------------------------------------------------------------------------
// Fused attention, K-split for occupancy:
//   grid (NS/32, NH, NB) = 2048 blocks -> 8 blocks/CU -> up to 32 waves/CU.
//   Block = 4 waves: qsub = wave&1 (which 16 q-rows), khalf = wave>>1 (which
//   half of the 2048 K range). Each wave's serial chain is halved vs before.
//   sweep 1: partial rowsums per k-half, cross-wave combine via tiny LDS.
//   sweep 2: recompute QK^T, normalize, per-wave LDS transpose, vectorized
//   f32x4 attn stores (replaces 16 scalar dword stores/lane), PV MFMA on the
//   k-half; PV partials combined across khalf pairs via LDS (reusing eLDS).
// ---------------------------------------------------------------------------
__global__ __launch_bounds__(256) void k_attn_pv(
    const bf16_t* __restrict__ q_ws, const bf16_t* __restrict__ k_ws,
    const bf16_t* __restrict__ v_ws, const int* __restrict__ mask,
    float* __restrict__ attn, bf16_t* __restrict__ o_ws)
{
  __shared__ __align__(16) float eLDS[4][16][68];  // per-wave 16x64 tile, +4 pad (17408 B)
  __shared__ float sLDS[2][2][16];                 // [khalf][qsub][row16] partial sums
  const int qt = blockIdx.x, h = blockIdx.y, b = blockIdx.z;
  const int wave = threadIdx.x >> 6, lane = threadIdx.x & 63;
  const int l16 = lane & 15, quad = lane >> 4;
  const int qsub = wave & 1, khalf = wave >> 1;
  const int qbase = qt * 32 + qsub * 16;
  const int kbase = khalf * (NS / 2);
  const long headoff = (long)(b * NH + h) * NS;
  const bf16_t* qhead = q_ws + headoff * NDH;
  const bf16_t* khead = k_ws + headoff * NDH;
  const bf16_t* vhead = v_ws + (long)(b * NH + h) * NDH * NS;
  const bf16x8 aq0 = load8(qhead + (long)(qbase + l16) * NDH + quad * 8);
  const bf16x8 aq1 = load8(qhead + (long)(qbase + l16) * NDH + 32 + quad * 8);
  const int* mrow = mask + b * NS;
  const int m0 = qbase + quad * 4;
  float* attn_head = attn + headoff * NS;

  // ---- sweep 1: partial rowsums over this wave's k-half ----
  float srow[4] = {0.f, 0.f, 0.f, 0.f};
  for (int k0 = kbase; k0 < kbase + NS / 2; k0 += 64) {
#pragma unroll
    for (int nt = 0; nt < 4; ++nt) {
      const bf16_t* kr = khead + (long)(k0 + nt * 16 + l16) * NDH;
      f32x4 acc = {0.f, 0.f, 0.f, 0.f};
      acc = __builtin_amdgcn_mfma_f32_16x16x32_bf16(aq0, load8(kr + quad * 8), acc, 0, 0, 0);
      acc = __builtin_amdgcn_mfma_f32_16x16x32_bf16(aq1, load8(kr + 32 + quad * 8), acc, 0, 0, 0);
      if (mrow[k0 + nt * 16 + l16]) {
#pragma unroll
        for (int r = 0; r < 4; ++r) srow[r] += __expf(acc[r]);
      }
    }
  }
#pragma unroll
  for (int r = 0; r < 4; ++r) {
    float v = srow[r];
    v += __shfl_xor(v, 1); v += __shfl_xor(v, 2);
    v += __shfl_xor(v, 4); v += __shfl_xor(v, 8);
    srow[r] = v;   // partial rowsum for row m0+r over this k-half
  }
  if (l16 == 0) {
#pragma unroll
    for (int r = 0; r < 4; ++r) sLDS[khalf][qsub][quad * 4 + r] = srow[r];
  }
  __syncthreads();
  float inv[4];
#pragma unroll
  for (int r = 0; r < 4; ++r)
    inv[r] = 1.0f / (sLDS[0][qsub][quad * 4 + r] + sLDS[1][qsub][quad * 4 + r]);

  // ---- sweep 2: recompute, normalize, store attn (vectorized), PV ----
  f32x4 acco[4] = {{0,0,0,0},{0,0,0,0},{0,0,0,0},{0,0,0,0}};
  for (int k0 = kbase; k0 < kbase + NS / 2; k0 += 64) {
#pragma unroll
    for (int nt = 0; nt < 4; ++nt) {
      const bf16_t* kr = khead + (long)(k0 + nt * 16 + l16) * NDH;
      f32x4 acc = {0.f, 0.f, 0.f, 0.f};
      acc = __builtin_amdgcn_mfma_f32_16x16x32_bf16(aq0, load8(kr + quad * 8), acc, 0, 0, 0);
      acc = __builtin_amdgcn_mfma_f32_16x16x32_bf16(aq1, load8(kr + 32 + quad * 8), acc, 0, 0, 0);
      const int mv = mrow[k0 + nt * 16 + l16];
#pragma unroll
      for (int r = 0; r < 4; ++r) {
        float e = mv ? __expf(acc[r]) * inv[r] : 0.0f;
        eLDS[wave][quad * 4 + r][nt * 16 + l16] = e;
      }
    }
    // per-wave LDS round-trip: this wave reads only rows it just wrote
    // (lockstep within wave; compiler inserts lgkmcnt wait)
    const float* rp = &eLDS[wave][l16][0];
    f32x4 e0 = *(const f32x4*)(rp + quad * 8);
    f32x4 e1 = *(const f32x4*)(rp + quad * 8 + 4);
    f32x4 e2 = *(const f32x4*)(rp + 32 + quad * 8);
    f32x4 e3 = *(const f32x4*)(rp + 32 + quad * 8 + 4);
    // vectorized final attn store from A-layout registers (4x dwordx4 / lane)
    float* ap = attn_head + (long)(qbase + l16) * NS + k0;
    *(f32x4*)(ap + quad * 8) = e0;
    *(f32x4*)(ap + quad * 8 + 4) = e1;
    *(f32x4*)(ap + 32 + quad * 8) = e2;
    *(f32x4*)(ap + 32 + quad * 8 + 4) = e3;
    bf16x8 af0, af1;
#pragma unroll
    for (int i = 0; i < 4; ++i) {
      af0[i] = (bf16_t)e0[i]; af0[i + 4] = (bf16_t)e1[i];
      af1[i] = (bf16_t)e2[i]; af1[i + 4] = (bf16_t)e3[i];
    }
#pragma unroll
    for (int nt = 0; nt < 4; ++nt) {
      const bf16_t* vr = vhead + (long)(nt * 16 + l16) * NS + k0;
      acco[nt] = __builtin_amdgcn_mfma_f32_16x16x32_bf16(af0, load8(vr + quad * 8), acco[nt], 0, 0, 0);
      acco[nt] = __builtin_amdgcn_mfma_f32_16x16x32_bf16(af1, load8(vr + 32 + quad * 8), acco[nt], 0, 0, 0);
    }
  }

  // ---- cross-wave k-half PV reduce (reuse eLDS as scratch: need 8 KB) ----
  __syncthreads();                       // all waves done with their eLDS tiles
  float* red = &eLDS[0][0][0];
  if (khalf == 1) {
    float* wp = red + ((qsub * 64 + lane) * 16);
#pragma unroll
    for (int nt = 0; nt < 4; ++nt) *(f32x4*)(wp + nt * 4) = acco[nt];
  }
  __syncthreads();
  if (khalf == 0) {
    const float* rr = red + ((qsub * 64 + lane) * 16);
#pragma unroll
    for (int nt = 0; nt < 4; ++nt) {
      f32x4 o = acco[nt] + *(const f32x4*)(rr + nt * 4);
      const int dh = nt * 16 + l16;
#pragma unroll
      for (int r = 0; r < 4; ++r)
        o_ws[(long)(b * NS + m0 + r) * NP + h * NDH + dh] = (bf16_t)o[r];
    }
  }
}

// ---------------------------------------------------------------------------
// out = O @ Wo  (fp32 store to d_out)
// ---------------------------------------------------------------------------
__global__ __launch_bounds__(256) void k_out(
    const bf16_t* __restrict__ o_ws, const bf16_t* __restrict__ wto,
    float* __restrict__ out)
{
  const int tm = blockIdx.x * 64, tn = blockIdx.y * 64;
  const int wave = threadIdx.x >> 6, lane = threadIdx.x & 63;
  const int l16 = lane & 15, quad = lane >> 4;
  const bf16_t* arow = o_ws + (long)(tm + wave * 16 + l16) * NP;
  const bf16_t* brow[4];
#pragma unroll
  for (int nt = 0; nt < 4; ++nt)
    brow[nt] = wto + (long)(tn + nt * 16 + l16) * NP;

  f32x4 acc[4] = {{0,0,0,0},{0,0,0,0},{0,0,0,0},{0,0,0,0}};
  for (int k0 = 0; k0 < NP; k0 += 32) {
    bf16x8 a = load8(arow + k0 + quad * 8);
#pragma unroll
    for (int nt = 0; nt < 4; ++nt) {
      bf16x8 bfrag = load8(brow[nt] + k0 + quad * 8);
      acc[nt] = __builtin_amdgcn_mfma_f32_16x16x32_bf16(a, bfrag, acc[nt], 0, 0, 0);
    }
  }
  const int m0 = tm + wave * 16 + quad * 4;
#pragma unroll
  for (int nt = 0; nt < 4; ++nt) {
    const int n = tn + nt * 16 + l16;
#pragma unroll
    for (int r = 0; r < 4; ++r)
      out[(long)(m0 + r) * NP + n] = acc[nt][r];
  }
}

// ---------------------------------------------------------------------------
extern "C" void kernel_launch(void* const* d_in, const int* in_sizes, int n_in,
                              void* d_out, int out_size, void* d_ws, size_t ws_size,
                              hipStream_t stream) {
  const float* x    = (const float*)d_in[0];
  const int*   mask = (const int*)d_in[1];
  const float* Wq   = (const float*)d_in[2];
  const float* Wk   = (const float*)d_in[3];
  const float* Wv   = (const float*)d_in[4];
  const float* Wo   = (const float*)d_in[5];

  float* out  = (float*)d_out;                    // [B,S,P] fp32
  float* attn = out + (long)NM * NP;              // [B,H,S,S] fp32

  char* ws = (char*)d_ws;
  const size_t MB = 1024 * 1024;
  bf16_t* x_bf  = (bf16_t*)(ws);                  // 8 MB (aliased as o_ws later)
  bf16_t* wtq   = (bf16_t*)(ws + 8  * MB);        // 2 MB each
  bf16_t* wtk   = (bf16_t*)(ws + 10 * MB);
  bf16_t* wtv   = (bf16_t*)(ws + 12 * MB);
  bf16_t* wto   = (bf16_t*)(ws + 14 * MB);
  bf16_t* q_ws  = (bf16_t*)(ws + 16 * MB);        // 8 MB [b][h][s][dh], pre-scaled 1/8
  bf16_t* k_ws  = (bf16_t*)(ws + 24 * MB);        // 8 MB [b][h][s][dh]
  bf16_t* v_ws  = (bf16_t*)(ws + 32 * MB);        // 8 MB [b][h][dh][s]
  bf16_t* o_ws  = x_bf;  // safe: x_bf consumed by k_gemm_proj before k_attn_pv writes

  k_cast<<<1024, 256, 0, stream>>>(x, x_bf);
  k_wt<<<dim3(ND / 64, NP / 64, 4), 256, 0, stream>>>(
      Wq, Wk, Wv, Wo, wtq, wtk, wtv, wto);
  k_gemm_proj<<<dim3(NM / 64, NP / 64, 3), 256, 0, stream>>>(
      x_bf, wtq, wtk, wtv, q_ws, k_ws, v_ws);
  k_attn_pv<<<dim3(NS / 32, NH, NB), 256, 0, stream>>>(
      q_ws, k_ws, v_ws, mask, attn, o_ws);
  k_out<<<dim3(NM / 64, NP / 64), 256, 0, stream>>>(o_ws, wto, out);
}